// Round 14
// baseline (126.224 us; speedup 1.0000x reference)
//
#include <hip/hip_runtime.h>
#include <hip/hip_bf16.h>

// ---- types ----
typedef float  f32x4  __attribute__((ext_vector_type(4)));
typedef __bf16 bf16x8 __attribute__((ext_vector_type(8)));
typedef __bf16 bf16x4 __attribute__((ext_vector_type(4)));
typedef __bf16 bf16x2 __attribute__((ext_vector_type(2)));

#define T_SEQ   2048
#define HIDDEN  2048
#define NH      32
#define NKV     4
#define HD      64
#define QSZ     2048
#define KVSZ    256
#define QKVN    2560
#define WINDOW  1024

#if __has_builtin(__builtin_amdgcn_exp2f)
#define EXPS(x) __builtin_amdgcn_exp2f(x)
#define QSCALE  0.1803368801111f   /* 0.125 * log2(e) */
#else
#define EXPS(x) __expf(x)
#define QSCALE  0.125f
#endif

#define RAW_BARRIER()   asm volatile("s_barrier" ::: "memory")
#define WAITV(n)        asm volatile("s_waitcnt vmcnt(" #n ")" ::: "memory")
#define WAITLGKM0()     asm volatile("s_waitcnt lgkmcnt(0)" ::: "memory")

__device__ __forceinline__ void gll16(const __bf16* g, __bf16* l) {
    __builtin_amdgcn_global_load_lds(
        (const __attribute__((address_space(1))) void*)g,
        (__attribute__((address_space(3))) void*)l,
        16, 0, 0);
}

// ================= prep kernel (ropetab + wqkv transpose) =================
// blocks [0,256): rope cos/sin table
// blocks [256,1536): transpose wqkv [2048][2560] -> bf16 [2560][2048]
__global__ __launch_bounds__(256) void prep(const float* __restrict__ wqkv,
                                            __bf16* __restrict__ wqkv_t,
                                            const int* __restrict__ pos,
                                            float2* __restrict__ ropetab) {
    __shared__ float tile[32][132];
    const int b = blockIdx.x;
    const int tid = threadIdx.x;

    if (b < 256) {
        int id = b * 256 + tid;               // 0..65535
        int row = id >> 5, f = id & 31;
        float p = (float)pos[row];
        float ifr = exp2f((float)f * -0.62286151779138f);
        float sn, cs;
        sincosf(p * ifr, &sn, &cs);
        ropetab[id] = make_float2(cs, sn);
        return;
    }

    int t = b - 256;                          // 0..1279 = 20 c-tiles x 64 r-tiles
    const int bx = t % 20, by = t / 20;
    const int ri = by * 32, ci = bx * 128;
    const int r0 = tid >> 5;
    const int c4 = tid & 31;
    #pragma unroll
    for (int i = 0; i < 4; i++) {
        float4 v = *reinterpret_cast<const float4*>(
            &wqkv[(size_t)(ri + r0 + i * 8) * QKVN + ci + c4 * 4]);
        *reinterpret_cast<float4*>(&tile[r0 + i * 8][c4 * 4]) = v;
    }
    __syncthreads();
    const int c  = tid >> 3;
    const int rb = tid & 7;
    #pragma unroll
    for (int j = 0; j < 4; j++) {
        int cc = c + j * 32;
        bf16x4 pk;
        #pragma unroll
        for (int i = 0; i < 4; i++) pk[i] = (__bf16)tile[rb * 4 + i][cc];
        *reinterpret_cast<bf16x4*>(&wqkv_t[(size_t)(ci + cc) * HIDDEN + ri + rb * 4]) = pk;
    }
}

// ================= GEMM core (shared macros) =================
// Tile 64(M) x 128(N), 256 threads = 4 waves, wave tile 32x64.

#define GEMM_IDX_COMMON()                                                       \
    const int tid = threadIdx.x;                                                \
    const int wid = tid >> 6;                                                   \
    const int l   = tid & 63;                                                   \
    const int lg  = l >> 4;                                                     \
    const int ll  = l & 15;                                                     \
    const int swl = ll & 7;                                                     \
    const int wm  = wid >> 1, wn = wid & 1;                                     \
    const int gx   = gridDim.x;                                                 \
    const int flat = blockIdx.y * gx + blockIdx.x;                              \
    const int nwg  = gx * gridDim.y;                                            \
    const int swz  = (flat & 7) * (nwg >> 3) + (flat >> 3);                     \
    const int bm   = (swz / gx) * 64;                                           \
    const int bn   = (swz % gx) * 128;                                          \
    f32x4 acc[2][4];                                                            \
    _Pragma("unroll")                                                           \
    for (int i = 0; i < 2; i++)                                                 \
        _Pragma("unroll")                                                       \
        for (int j = 0; j < 4; j++)                                             \
            acc[i][j] = (f32x4){0.f, 0.f, 0.f, 0.f};                            \
    const int srow = tid >> 3;                                                  \
    const int sseg0 = tid & 7;

#define GEMM_STAGE(buf, k0, Kdim)                                               \
    {                                                                           \
        _Pragma("unroll")                                                       \
        for (int c = 0; c < 2; c++) {                                           \
            int row  = c * 32 + srow;                                           \
            int sseg = sseg0 ^ (row & 7);                                       \
            gll16(Ab + (size_t)row * (Kdim) + (k0) + sseg * 8,                  \
                  &Asm[buf][(c * 256 + tid) * 8]);                              \
        }                                                                       \
        _Pragma("unroll")                                                       \
        for (int c = 0; c < 4; c++) {                                           \
            int row  = c * 32 + srow;                                           \
            int sseg = sseg0 ^ (row & 7);                                       \
            gll16(Bb + (size_t)row * (Kdim) + (k0) + sseg * 8,                  \
                  &Bsm[buf][(c * 256 + tid) * 8]);                              \
        }                                                                       \
    }

#define GEMM_COMPUTE(bufidx)                                                    \
    _Pragma("unroll")                                                           \
    for (int ss = 0; ss < 2; ss++) {                                            \
        bf16x8 af[2], bfr[4];                                                   \
        _Pragma("unroll")                                                       \
        for (int mi = 0; mi < 2; mi++) {                                        \
            int r = wm * 32 + mi * 16 + ll;                                     \
            int u = (ss * 4 + lg) ^ swl;                                        \
            af[mi] = *reinterpret_cast<const bf16x8*>(&Asm[bufidx][r * 64 + u * 8]); \
        }                                                                       \
        _Pragma("unroll")                                                       \
        for (int ni = 0; ni < 4; ni++) {                                        \
            int r = wn * 64 + ni * 16 + ll;                                     \
            int u = (ss * 4 + lg) ^ swl;                                        \
            bfr[ni] = *reinterpret_cast<const bf16x8*>(&Bsm[bufidx][r * 64 + u * 8]); \
        }                                                                       \
        _Pragma("unroll")                                                       \
        for (int mi = 0; mi < 2; mi++)                                          \
            _Pragma("unroll")                                                   \
            for (int ni = 0; ni < 4; ni++)                                      \
                acc[mi][ni] = __builtin_amdgcn_mfma_f32_16x16x32_bf16(          \
                    af[mi], bfr[ni], acc[mi][ni], 0, 0, 0);                     \
    }

// 3-buffer loop, single barrier per tile, 2-deep prefetch (72 KB; gemm_out)
#define GEMM_KLOOP3(Kdim)                                                       \
    GEMM_STAGE(0, 0, Kdim)                                                      \
    GEMM_STAGE(1, 64, Kdim)                                                     \
    int cur = 0;                                                                \
    for (int k0 = 0; k0 < (Kdim); k0 += 64) {                                   \
        if (k0 + 64 < (Kdim)) { WAITV(6); } else { WAITV(0); }                  \
        RAW_BARRIER();                                                          \
        __builtin_amdgcn_sched_barrier(0);                                      \
        if (k0 + 128 < (Kdim)) {                                                \
            int nb = cur + 2; if (nb >= 3) nb -= 3;                             \
            GEMM_STAGE(nb, k0 + 128, Kdim)                                      \
        }                                                                       \
        GEMM_COMPUTE(cur)                                                       \
        cur = (cur == 2) ? 0 : cur + 1;                                         \
    }

// ---------------- GEMM2: C[M][N] = A * Bt^T, fp32 out ----------------
__global__ __launch_bounds__(256) void gemm_out(const __bf16* __restrict__ A,
                                                const __bf16* __restrict__ Bt,
                                                float* __restrict__ Cout,
                                                int M, int N, int K) {
    __shared__ __align__(16) __bf16 Asm[3][64 * 64];
    __shared__ __align__(16) __bf16 Bsm[3][128 * 64];
    GEMM_IDX_COMMON()
    const __bf16* Ab = A  + (size_t)bm * K;
    const __bf16* Bb = Bt + (size_t)bn * K;
    GEMM_KLOOP3(K)
    #pragma unroll
    for (int mi = 0; mi < 2; mi++)
        #pragma unroll
        for (int ni = 0; ni < 4; ni++)
            #pragma unroll
            for (int r = 0; r < 4; r++) {
                int row = bm + wm*32 + mi*16 + lg*4 + r;
                int col = bn + wn*64 + ni*16 + ll;
                Cout[(size_t)row * N + col] = acc[mi][ni][r];
            }
}

// ---------------- GEMM1 fused: qkv proj (A = hidden f32, converted in-stage)
//                  + RoPE(table) + split + V-transpose ----------------
// A reg-staged: float4 x2 loads -> cvt -> ds_write (same swizzled LDS layout);
// B via gll16. Counted vmcnt: A-loads issued FIRST so WAITV(4) retires
// {B_cur(4), A_next(2)} leaving B_next(4) in flight.
__global__ __launch_bounds__(256) void gemm_qkv(const float* __restrict__ Af,
                                                const __bf16* __restrict__ Bt,
                                                const float2* __restrict__ ropetab,
                                                __bf16* __restrict__ q,
                                                __bf16* __restrict__ k,
                                                __bf16* __restrict__ vT) {
    __shared__ __align__(16) __bf16 Asm[2][64 * 64];
    __shared__ __align__(16) __bf16 Bsm[2][128 * 64];
    GEMM_IDX_COMMON()
    const float*  Ab = Af + (size_t)bm * HIDDEN;
    const __bf16* Bb = Bt + (size_t)bn * HIDDEN;

#define QKV_A_LOAD(k0)                                                          \
    _Pragma("unroll")                                                           \
    for (int c = 0; c < 2; c++) {                                               \
        int row  = c * 32 + srow;                                               \
        int useg = sseg0 ^ (row & 7);                                           \
        const float4* src = reinterpret_cast<const float4*>(                    \
            Ab + (size_t)row * HIDDEN + (k0) + useg * 8);                       \
        fa[c][0] = src[0];                                                      \
        fa[c][1] = src[1];                                                      \
    }

#define QKV_A_WRITE(buf)                                                        \
    _Pragma("unroll")                                                           \
    for (int c = 0; c < 2; c++) {                                               \
        bf16x8 w;                                                               \
        w[0] = (__bf16)fa[c][0].x; w[1] = (__bf16)fa[c][0].y;                   \
        w[2] = (__bf16)fa[c][0].z; w[3] = (__bf16)fa[c][0].w;                   \
        w[4] = (__bf16)fa[c][1].x; w[5] = (__bf16)fa[c][1].y;                   \
        w[6] = (__bf16)fa[c][1].z; w[7] = (__bf16)fa[c][1].w;                   \
        *reinterpret_cast<bf16x8*>(&Asm[buf][(c * 256 + tid) * 8]) = w;         \
    }

#define QKV_B_STAGE(buf, k0)                                                    \
    _Pragma("unroll")                                                           \
    for (int c = 0; c < 4; c++) {                                               \
        int row  = c * 32 + srow;                                               \
        int sseg = sseg0 ^ (row & 7);                                           \
        gll16(Bb + (size_t)row * HIDDEN + (k0) + sseg * 8,                      \
              &Bsm[buf][(c * 256 + tid) * 8]);                                  \
    }

    float4 fa[2][2];
    // prologue: tile 0
    QKV_A_LOAD(0)
    QKV_B_STAGE(0, 0)
    WAITV(4);            // A0 in regs; B0(4) outstanding
    QKV_A_WRITE(0)

    int cur = 0;
    for (int k0 = 0; k0 < HIDDEN; k0 += 64) {
        RAW_BARRIER();   // read-done for buffer being overwritten
        if (k0 + 64 < HIDDEN) {
            QKV_A_LOAD(k0 + 64)
            QKV_B_STAGE(cur ^ 1, k0 + 64)
            WAITV(4);    // retires B_cur(4)+A_next(2); B_next(4) in flight
            QKV_A_WRITE(cur ^ 1)
            WAITLGKM0(); // ds_writes (this + prologue) visible before publish
        } else {
            WAITV(0);
            WAITLGKM0();
        }
        RAW_BARRIER();   // publish tile cur
        __builtin_amdgcn_sched_barrier(0);
        GEMM_COMPUTE(cur)
        cur ^= 1;
    }
#undef QKV_A_LOAD
#undef QKV_A_WRITE
#undef QKV_B_STAGE

    if (bn < QSZ + KVSZ) {
        const bool isq = (bn < QSZ);
        #pragma unroll
        for (int mi = 0; mi < 2; mi++) {
            #pragma unroll
            for (int r = 0; r < 4; r++) {
                int row = bm + wm*32 + mi*16 + lg*4 + r;
                const float2* tb = &ropetab[row * 32 + ll];
                #pragma unroll
                for (int ni = 0; ni < 2; ni++) {
                    float2 cssn = tb[ni * 16];
                    float x1 = acc[mi][ni][r], x2 = acc[mi][ni + 2][r];
                    float o1 = x1 * cssn.x - x2 * cssn.y;
                    float o2 = x2 * cssn.x + x1 * cssn.y;
                    int col = bn + wn*64 + ni*16 + ll;
                    if (isq) {
                        q[(size_t)row * QSZ + col]      = (__bf16)(o1 * QSCALE);
                        q[(size_t)row * QSZ + col + 32] = (__bf16)(o2 * QSCALE);
                    } else {
                        k[(size_t)row * KVSZ + (col - QSZ)]      = (__bf16)o1;
                        k[(size_t)row * KVSZ + (col - QSZ) + 32] = (__bf16)o2;
                    }
                }
            }
        }
    } else {
        #pragma unroll
        for (int mi = 0; mi < 2; mi++) {
            int row0 = bm + wm*32 + mi*16 + lg*4;
            #pragma unroll
            for (int ni = 0; ni < 4; ni++) {
                int d = bn + wn*64 + ni*16 + ll - (QSZ + KVSZ);
                bf16x4 pk;
                #pragma unroll
                for (int r = 0; r < 4; r++) pk[r] = (__bf16)acc[mi][ni][r];
                *reinterpret_cast<bf16x4*>(&vT[(size_t)d * T_SEQ + row0]) = pk;
            }
        }
    }
}

// ---------------- attn (blocks 0..511) + wo transpose (blocks 512..1535) ----------------
__global__ __launch_bounds__(512) void attn_fused(const __bf16* __restrict__ qg,
                                                  const __bf16* __restrict__ kgl,
                                                  const __bf16* __restrict__ vTg,
                                                  __bf16* __restrict__ og,
                                                  const float* __restrict__ wo,
                                                  __bf16* __restrict__ wo_t) {
    __shared__ __align__(16) char smem[49152];
    const int b   = blockIdx.x;
    const int tid = threadIdx.x;

    if (b >= 512) {
        float (*tile)[132] = (float(*)[132])smem;
        int t = b - 512;                       // 0..1023 = 16 c-tiles x 64 r-tiles
        const int bx = t & 15, by = t >> 4;
        const int ri = by * 32, ci = bx * 128;
        const int r0 = tid >> 4;
        const int c8 = tid & 15;
        #pragma unroll
        for (int j = 0; j < 2; j++) {
            int col = c8 * 8 + j * 4;
            float4 v = *reinterpret_cast<const float4*>(
                &wo[(size_t)(ri + r0) * HIDDEN + ci + col]);
            *reinterpret_cast<float4*>(&tile[r0][col]) = v;
        }
        __syncthreads();
        #pragma unroll
        for (int j = 0; j < 2; j++) {
            int u  = tid + j * 512;
            int cc = u >> 3;
            int rb = u & 7;
            bf16x4 pk;
            #pragma unroll
            for (int i = 0; i < 4; i++) pk[i] = (__bf16)tile[rb * 4 + i][cc];
            *reinterpret_cast<bf16x4*>(&wo_t[(size_t)(ci + cc) * HIDDEN + ri + rb * 4]) = pk;
        }
        return;
    }

    __bf16* Ksm = (__bf16*)smem;               // [3][4096]
    __bf16* VTs = (__bf16*)(smem + 24576);     // [3][4096]
#define KSM(buf) (Ksm + (buf) * 4096)
#define VSM(buf) (VTs + (buf) * 4096)

    const int qb  = b & 31;
    const int hp  = b >> 5;
    const int kvh = hp >> 2;
    const int wid = tid >> 6;
    const int h   = hp * 2 + (wid >> 2);
    const int l   = tid & 63;
    const int lg  = l >> 4;
    const int ll  = l & 15;
    const int i0  = qb * 64;
    const int qw  = i0 + (wid & 3) * 16;
    const int qi  = qw + ll;

    bf16x8 qf[2];
    {
        const __bf16* qp = qg + (size_t)(qw + ll) * QSZ + h * 64 + lg * 8;
        qf[0] = *reinterpret_cast<const bf16x8*>(qp);
        qf[1] = *reinterpret_cast<const bf16x8*>(qp + 32);
    }

    f32x4 o[4];
    #pragma unroll
    for (int dn = 0; dn < 4; dn++) o[dn] = (f32x4){0.f, 0.f, 0.f, 0.f};
    float l_run = 0.f;

    int jlo = i0 - (WINDOW - 1); if (jlo < 0) jlo = 0;
    int t0v = jlo & ~63;
    int tend = i0 + 64;

    const int srow = tid >> 3;
    const int sg   = (tid & 7) ^ (srow & 7);
    const int krow = (srow & 35) | ((srow & 8) << 1) | ((srow & 4) << 1) | ((srow & 16) >> 2);
    const __bf16* kp = kgl + (size_t)krow * KVSZ + kvh * 64 + sg * 8;
    const __bf16* vp = vTg + (size_t)(kvh * 64 + srow) * T_SEQ + sg * 8;

#define ASTAGE(buf, t)                                   \
    {                                                    \
        gll16(kp + (size_t)(t) * KVSZ, KSM(buf) + tid * 8); \
        gll16(vp + (t),                VSM(buf) + tid * 8); \
    }

    ASTAGE(0, t0v);
    if (t0v + 64 < tend) ASTAGE(1, t0v + 64);

    const int swl = ll & 7;
    const int u0 = (lg ^ swl) * 8;
    const int u1 = ((4 + lg) ^ swl) * 8;

    int cur = 0;
    for (int t = t0v; t < tend; t += 64) {
        if (t + 64 < tend) { WAITV(2); } else { WAITV(0); }
        RAW_BARRIER();
        __builtin_amdgcn_sched_barrier(0);
        if (t + 128 < tend) {
            int nb = cur + 2; if (nb >= 3) nb -= 3;
            ASTAGE(nb, t + 128);
        }

        bool active = (t <= qw + 15) && (t + 63 >= qw - (WINDOW - 1));
        if (active) {
            f32x4 sT[4];
            __builtin_amdgcn_s_setprio(1);
            #pragma unroll
            for (int kt = 0; kt < 4; kt++) {
                sT[kt] = (f32x4){0.f, 0.f, 0.f, 0.f};
                bf16x8 kf0 = *reinterpret_cast<const bf16x8*>(KSM(cur) + kt*1024 + ll*64 + u0);
                sT[kt] = __builtin_amdgcn_mfma_f32_16x16x32_bf16(kf0, qf[0], sT[kt], 0, 0, 0);
                bf16x8 kf1 = *reinterpret_cast<const bf16x8*>(KSM(cur) + kt*1024 + ll*64 + u1);
                sT[kt] = __builtin_amdgcn_mfma_f32_16x16x32_bf16(kf1, qf[1], sT[kt], 0, 0, 0);
            }
            __builtin_amdgcn_s_setprio(0);

            bool full = (t + 63 <= qw) && (t >= qw + 15 - (WINDOW - 1));
            float ts = 0.f;
            if (full) {
                #pragma unroll
                for (int kt = 0; kt < 4; kt++) {
                    #pragma unroll
                    for (int r = 0; r < 4; r++) {
                        float p = EXPS(sT[kt][r]);
                        sT[kt][r] = p;
                        ts += p;
                    }
                }
            } else {
                #pragma unroll
                for (int kt = 0; kt < 4; kt++) {
                    int jb = t + ((kt & 2) << 4) + ((kt & 1) << 2) + (lg << 3);
                    #pragma unroll
                    for (int r = 0; r < 4; r++) {
                        int j = jb + r;
                        bool ok = (j <= qi) && (qi - j < WINDOW);
                        float p = ok ? EXPS(sT[kt][r]) : 0.f;
                        sT[kt][r] = p;
                        ts += p;
                    }
                }
            }
            ts += __shfl_xor(ts, 16);
            ts += __shfl_xor(ts, 32);
            l_run += ts;

            __builtin_amdgcn_s_setprio(1);
            #pragma unroll
            for (int kt2 = 0; kt2 < 2; kt2++) {
                bf16x8 pa;
                #pragma unroll
                for (int r = 0; r < 4; r++) {
                    pa[r]     = (__bf16)sT[kt2*2][r];
                    pa[r + 4] = (__bf16)sT[kt2*2 + 1][r];
                }
                int uv = kt2 ? u1 : u0;
                #pragma unroll
                for (int dn = 0; dn < 4; dn++) {
                    bf16x8 vf = *reinterpret_cast<const bf16x8*>(VSM(cur) + dn*1024 + ll*64 + uv);
                    o[dn] = __builtin_amdgcn_mfma_f32_16x16x32_bf16(pa, vf, o[dn], 0, 0, 0);
                }
            }
            __builtin_amdgcn_s_setprio(0);
        }
        cur = (cur == 2) ? 0 : cur + 1;
    }
#undef ASTAGE
#undef KSM
#undef VSM

    float linv = 1.0f / l_run;
    float i0v = __shfl(linv, lg*4 + 0);
    float i1v = __shfl(linv, lg*4 + 1);
    float i2v = __shfl(linv, lg*4 + 2);
    float i3v = __shfl(linv, lg*4 + 3);
    #pragma unroll
    for (int dn = 0; dn < 4; dn++) {
        og[(size_t)(qw + lg*4 + 0) * QSZ + h*64 + dn*16 + ll] = (__bf16)(o[dn][0] * i0v);
        og[(size_t)(qw + lg*4 + 1) * QSZ + h*64 + dn*16 + ll] = (__bf16)(o[dn][1] * i1v);
        og[(size_t)(qw + lg*4 + 2) * QSZ + h*64 + dn*16 + ll] = (__bf16)(o[dn][2] * i2v);
        og[(size_t)(qw + lg*4 + 3) * QSZ + h*64 + dn*16 + ll] = (__bf16)(o[dn][3] * i3v);
    }
}

// ---------------- launch ----------------
extern "C" void kernel_launch(void* const* d_in, const int* in_sizes, int n_in,
                              void* d_out, int out_size, void* d_ws, size_t ws_size,
                              hipStream_t stream) {
    const int*   positions = (const int*)d_in[0];
    const float* hidden    = (const float*)d_in[1];
    const float* wqkv      = (const float*)d_in[2];
    const float* wo        = (const float*)d_in[3];
    float* out = (float*)d_out;

    char* ws = (char*)d_ws;
    __bf16* wqkv_t    = (__bf16*)(ws + 8388608);             // 2560x2048
    __bf16* wo_t      = (__bf16*)(ws + 18874368);            // 2048x2048
    __bf16* q_bf      = (__bf16*)(ws + 37748736);            // 2048x2048
    __bf16* k_bf      = (__bf16*)(ws + 46137344);            // 2048x256
    __bf16* vT_bf     = (__bf16*)(ws + 47185920);            // 256x2048 (V^T)
    __bf16* attn_bf   = (__bf16*)(ws + 48234496);            // 2048x2048
    float2* ropetab   = (float2*)(ws + 56623104);            // 2048x32 float2

    prep<<<dim3(1536), dim3(256), 0, stream>>>(
        wqkv, wqkv_t, positions, ropetab);

    gemm_qkv<<<dim3(QKVN / 128, T_SEQ / 64), dim3(256), 0, stream>>>(
        hidden, wqkv_t, ropetab, q_bf, k_bf, vT_bf);

    attn_fused<<<dim3(1536), dim3(512), 0, stream>>>(
        q_bf, k_bf, vT_bf, attn_bf, wo, wo_t);

    gemm_out<<<dim3(HIDDEN / 128, T_SEQ / 64), dim3(256), 0, stream>>>(
        attn_bf, wo_t, out, T_SEQ, HIDDEN, QSZ);
}

// Round 15
// 101.581 us; speedup vs baseline: 1.2426x; 1.2426x over previous
//
#include <hip/hip_runtime.h>
#include <hip/hip_bf16.h>

// ---- types ----
typedef float  f32x4  __attribute__((ext_vector_type(4)));
typedef __bf16 bf16x8 __attribute__((ext_vector_type(8)));
typedef __bf16 bf16x4 __attribute__((ext_vector_type(4)));
typedef __bf16 bf16x2 __attribute__((ext_vector_type(2)));

#define T_SEQ   2048
#define HIDDEN  2048
#define NH      32
#define NKV     4
#define HD      64
#define QSZ     2048
#define KVSZ    256
#define QKVN    2560
#define WINDOW  1024

#if __has_builtin(__builtin_amdgcn_exp2f)
#define EXPS(x) __builtin_amdgcn_exp2f(x)
#define QSCALE  0.1803368801111f   /* 0.125 * log2(e) */
#else
#define EXPS(x) __expf(x)
#define QSCALE  0.125f
#endif

#define RAW_BARRIER()   asm volatile("s_barrier" ::: "memory")
#define WAITV(n)        asm volatile("s_waitcnt vmcnt(" #n ")" ::: "memory")

__device__ __forceinline__ void gll16(const __bf16* g, __bf16* l) {
    __builtin_amdgcn_global_load_lds(
        (const __attribute__((address_space(1))) void*)g,
        (__attribute__((address_space(3))) void*)l,
        16, 0, 0);
}

// ================= prep kernel (hidden cvt + ropetab + wqkv transpose) =================
// blocks [0,4096): hidden f32 -> bf16
// blocks [4096,4352): rope cos/sin table
// blocks [4352,5632): transpose wqkv [2048][2560] -> bf16 [2560][2048]
__global__ __launch_bounds__(256) void prep(const float4* __restrict__ hidden4,
                                            bf16x4* __restrict__ hidden_bf4,
                                            const float* __restrict__ wqkv,
                                            __bf16* __restrict__ wqkv_t,
                                            const int* __restrict__ pos,
                                            float2* __restrict__ ropetab) {
    __shared__ float tile[32][132];
    const int b = blockIdx.x;
    const int tid = threadIdx.x;

    if (b < 4096) {
        int id = b * 256 + tid;
        float4 v = hidden4[id];
        bf16x4 o;
        o[0] = (__bf16)v.x; o[1] = (__bf16)v.y; o[2] = (__bf16)v.z; o[3] = (__bf16)v.w;
        hidden_bf4[id] = o;
        return;
    }
    if (b < 4352) {
        int id = (b - 4096) * 256 + tid;
        int row = id >> 5, f = id & 31;
        float p = (float)pos[row];
        float ifr = exp2f((float)f * -0.62286151779138f);
        float sn, cs;
        sincosf(p * ifr, &sn, &cs);
        ropetab[id] = make_float2(cs, sn);
        return;
    }

    int t = b - 4352;                     // 0..1279 = 20 c-tiles x 64 r-tiles
    const int bx = t % 20, by = t / 20;
    const int ri = by * 32, ci = bx * 128;
    const int r0 = tid >> 5;
    const int c4 = tid & 31;
    #pragma unroll
    for (int i = 0; i < 4; i++) {
        float4 v = *reinterpret_cast<const float4*>(
            &wqkv[(size_t)(ri + r0 + i * 8) * QKVN + ci + c4 * 4]);
        *reinterpret_cast<float4*>(&tile[r0 + i * 8][c4 * 4]) = v;
    }
    __syncthreads();
    const int c  = tid >> 3;
    const int rb = tid & 7;
    #pragma unroll
    for (int j = 0; j < 4; j++) {
        int cc = c + j * 32;
        bf16x4 pk;
        #pragma unroll
        for (int i = 0; i < 4; i++) pk[i] = (__bf16)tile[rb * 4 + i][cc];
        *reinterpret_cast<bf16x4*>(&wqkv_t[(size_t)(ci + cc) * HIDDEN + ri + rb * 4]) = pk;
    }
}

// ================= GEMM core (shared macros) =================
// Tile 64(M) x 128(N), 256 threads = 4 waves, wave tile 32x64.

#define GEMM_PROLOGUE_COMMON(Aptr, Btptr, Kdim)                                 \
    const int tid = threadIdx.x;                                                \
    const int wid = tid >> 6;                                                   \
    const int l   = tid & 63;                                                   \
    const int lg  = l >> 4;                                                     \
    const int ll  = l & 15;                                                     \
    const int swl = ll & 7;                                                     \
    const int wm  = wid >> 1, wn = wid & 1;                                     \
    const int gx   = gridDim.x;                                                 \
    const int flat = blockIdx.y * gx + blockIdx.x;                              \
    const int nwg  = gx * gridDim.y;                                            \
    const int swz  = (flat & 7) * (nwg >> 3) + (flat >> 3);                     \
    const int bm   = (swz / gx) * 64;                                           \
    const int bn   = (swz % gx) * 128;                                          \
    const __bf16* Ab = (Aptr) + (size_t)bm * (Kdim);                            \
    const __bf16* Bb = (Btptr) + (size_t)bn * (Kdim);                           \
    f32x4 acc[2][4];                                                            \
    _Pragma("unroll")                                                           \
    for (int i = 0; i < 2; i++)                                                 \
        _Pragma("unroll")                                                       \
        for (int j = 0; j < 4; j++)                                             \
            acc[i][j] = (f32x4){0.f, 0.f, 0.f, 0.f};                            \
    const int srow = tid >> 3;                                                  \
    const int sseg0 = tid & 7;

#define GEMM_STAGE(buf, k0, Kdim)                                               \
    {                                                                           \
        _Pragma("unroll")                                                       \
        for (int c = 0; c < 2; c++) {                                           \
            int row  = c * 32 + srow;                                           \
            int sseg = sseg0 ^ (row & 7);                                       \
            gll16(Ab + (size_t)row * (Kdim) + (k0) + sseg * 8,                  \
                  &Asm[buf][(c * 256 + tid) * 8]);                              \
        }                                                                       \
        _Pragma("unroll")                                                       \
        for (int c = 0; c < 4; c++) {                                           \
            int row  = c * 32 + srow;                                           \
            int sseg = sseg0 ^ (row & 7);                                       \
            gll16(Bb + (size_t)row * (Kdim) + (k0) + sseg * 8,                  \
                  &Bsm[buf][(c * 256 + tid) * 8]);                              \
        }                                                                       \
    }

#define GEMM_COMPUTE(bufidx)                                                    \
    _Pragma("unroll")                                                           \
    for (int ss = 0; ss < 2; ss++) {                                            \
        bf16x8 af[2], bfr[4];                                                   \
        _Pragma("unroll")                                                       \
        for (int mi = 0; mi < 2; mi++) {                                        \
            int r = wm * 32 + mi * 16 + ll;                                     \
            int u = (ss * 4 + lg) ^ swl;                                        \
            af[mi] = *reinterpret_cast<const bf16x8*>(&Asm[bufidx][r * 64 + u * 8]); \
        }                                                                       \
        _Pragma("unroll")                                                       \
        for (int ni = 0; ni < 4; ni++) {                                        \
            int r = wn * 64 + ni * 16 + ll;                                     \
            int u = (ss * 4 + lg) ^ swl;                                        \
            bfr[ni] = *reinterpret_cast<const bf16x8*>(&Bsm[bufidx][r * 64 + u * 8]); \
        }                                                                       \
        _Pragma("unroll")                                                       \
        for (int mi = 0; mi < 2; mi++)                                          \
            _Pragma("unroll")                                                   \
            for (int ni = 0; ni < 4; ni++)                                      \
                acc[mi][ni] = __builtin_amdgcn_mfma_f32_16x16x32_bf16(          \
                    af[mi], bfr[ni], acc[mi][ni], 0, 0, 0);                     \
    }

// 2-buffer counted loop (48 KB LDS)
#define GEMM_KLOOP2(Kdim)                                                       \
    GEMM_STAGE(0, 0, Kdim)                                                      \
    int cur = 0;                                                                \
    for (int k0 = 0; k0 < (Kdim); k0 += 64) {                                   \
        RAW_BARRIER();                                                          \
        if (k0 + 64 < (Kdim)) {                                                 \
            GEMM_STAGE(cur ^ 1, k0 + 64, Kdim)                                  \
            WAITV(6);                                                           \
        } else {                                                                \
            WAITV(0);                                                           \
        }                                                                       \
        RAW_BARRIER();                                                          \
        __builtin_amdgcn_sched_barrier(0);                                      \
        GEMM_COMPUTE(cur)                                                       \
        cur ^= 1;                                                               \
    }

// 3-buffer loop, single barrier per tile, 2-deep prefetch (72 KB)
#define GEMM_KLOOP3(Kdim)                                                       \
    GEMM_STAGE(0, 0, Kdim)                                                      \
    GEMM_STAGE(1, 64, Kdim)                                                     \
    int cur = 0;                                                                \
    for (int k0 = 0; k0 < (Kdim); k0 += 64) {                                   \
        if (k0 + 64 < (Kdim)) { WAITV(6); } else { WAITV(0); }                  \
        RAW_BARRIER();                                                          \
        __builtin_amdgcn_sched_barrier(0);                                      \
        if (k0 + 128 < (Kdim)) {                                                \
            int nb = cur + 2; if (nb >= 3) nb -= 3;                             \
            GEMM_STAGE(nb, k0 + 128, Kdim)                                      \
        }                                                                       \
        GEMM_COMPUTE(cur)                                                       \
        cur = (cur == 2) ? 0 : cur + 1;                                         \
    }

// ---------------- GEMM2: C[M][N] = A * Bt^T, fp32 out ----------------
__global__ __launch_bounds__(256) void gemm_out(const __bf16* __restrict__ A,
                                                const __bf16* __restrict__ Bt,
                                                float* __restrict__ Cout,
                                                int M, int N, int K) {
    __shared__ __align__(16) __bf16 Asm[3][64 * 64];
    __shared__ __align__(16) __bf16 Bsm[3][128 * 64];
    GEMM_PROLOGUE_COMMON(A, Bt, K)
    GEMM_KLOOP3(K)
    #pragma unroll
    for (int mi = 0; mi < 2; mi++)
        #pragma unroll
        for (int ni = 0; ni < 4; ni++)
            #pragma unroll
            for (int r = 0; r < 4; r++) {
                int row = bm + wm*32 + mi*16 + lg*4 + r;
                int col = bn + wn*64 + ni*16 + ll;
                Cout[(size_t)row * N + col] = acc[mi][ni][r];
            }
}

// ---------------- GEMM1 fused: qkv proj + RoPE(table) + split + V-transpose ----------------
__global__ __launch_bounds__(256) void gemm_qkv(const __bf16* __restrict__ A,
                                                const __bf16* __restrict__ Bt,
                                                const float2* __restrict__ ropetab,
                                                __bf16* __restrict__ q,
                                                __bf16* __restrict__ k,
                                                __bf16* __restrict__ vT) {
    __shared__ __align__(16) __bf16 Asm[2][64 * 64];
    __shared__ __align__(16) __bf16 Bsm[2][128 * 64];
    GEMM_PROLOGUE_COMMON(A, Bt, HIDDEN)
    GEMM_KLOOP2(HIDDEN)

    if (bn < QSZ + KVSZ) {
        const bool isq = (bn < QSZ);
        #pragma unroll
        for (int mi = 0; mi < 2; mi++) {
            #pragma unroll
            for (int r = 0; r < 4; r++) {
                int row = bm + wm*32 + mi*16 + lg*4 + r;
                const float2* tb = &ropetab[row * 32 + ll];
                #pragma unroll
                for (int ni = 0; ni < 2; ni++) {
                    float2 cssn = tb[ni * 16];
                    float x1 = acc[mi][ni][r], x2 = acc[mi][ni + 2][r];
                    float o1 = x1 * cssn.x - x2 * cssn.y;
                    float o2 = x2 * cssn.x + x1 * cssn.y;
                    int col = bn + wn*64 + ni*16 + ll;
                    if (isq) {
                        q[(size_t)row * QSZ + col]      = (__bf16)(o1 * QSCALE);
                        q[(size_t)row * QSZ + col + 32] = (__bf16)(o2 * QSCALE);
                    } else {
                        k[(size_t)row * KVSZ + (col - QSZ)]      = (__bf16)o1;
                        k[(size_t)row * KVSZ + (col - QSZ) + 32] = (__bf16)o2;
                    }
                }
            }
        }
    } else {
        #pragma unroll
        for (int mi = 0; mi < 2; mi++) {
            int row0 = bm + wm*32 + mi*16 + lg*4;
            #pragma unroll
            for (int ni = 0; ni < 4; ni++) {
                int d = bn + wn*64 + ni*16 + ll - (QSZ + KVSZ);
                bf16x4 pk;
                #pragma unroll
                for (int r = 0; r < 4; r++) pk[r] = (__bf16)acc[mi][ni][r];
                *reinterpret_cast<bf16x4*>(&vT[(size_t)d * T_SEQ + row0]) = pk;
            }
        }
    }
}

// ---------------- attn (blocks 0..511) + wo transpose (blocks 512..1535) ----------------
__global__ __launch_bounds__(512) void attn_fused(const __bf16* __restrict__ qg,
                                                  const __bf16* __restrict__ kgl,
                                                  const __bf16* __restrict__ vTg,
                                                  __bf16* __restrict__ og,
                                                  const float* __restrict__ wo,
                                                  __bf16* __restrict__ wo_t) {
    __shared__ __align__(16) char smem[49152];
    const int b   = blockIdx.x;
    const int tid = threadIdx.x;

    if (b >= 512) {
        float (*tile)[132] = (float(*)[132])smem;
        int t = b - 512;                       // 0..1023 = 16 c-tiles x 64 r-tiles
        const int bx = t & 15, by = t >> 4;
        const int ri = by * 32, ci = bx * 128;
        const int r0 = tid >> 4;
        const int c8 = tid & 15;
        #pragma unroll
        for (int j = 0; j < 2; j++) {
            int col = c8 * 8 + j * 4;
            float4 v = *reinterpret_cast<const float4*>(
                &wo[(size_t)(ri + r0) * HIDDEN + ci + col]);
            *reinterpret_cast<float4*>(&tile[r0][col]) = v;
        }
        __syncthreads();
        #pragma unroll
        for (int j = 0; j < 2; j++) {
            int u  = tid + j * 512;
            int cc = u >> 3;
            int rb = u & 7;
            bf16x4 pk;
            #pragma unroll
            for (int i = 0; i < 4; i++) pk[i] = (__bf16)tile[rb * 4 + i][cc];
            *reinterpret_cast<bf16x4*>(&wo_t[(size_t)(ci + cc) * HIDDEN + ri + rb * 4]) = pk;
        }
        return;
    }

    __bf16* Ksm = (__bf16*)smem;               // [3][4096]
    __bf16* VTs = (__bf16*)(smem + 24576);     // [3][4096]
#define KSM(buf) (Ksm + (buf) * 4096)
#define VSM(buf) (VTs + (buf) * 4096)

    const int qb  = b & 31;
    const int hp  = b >> 5;
    const int kvh = hp >> 2;
    const int wid = tid >> 6;
    const int h   = hp * 2 + (wid >> 2);
    const int l   = tid & 63;
    const int lg  = l >> 4;
    const int ll  = l & 15;
    const int i0  = qb * 64;
    const int qw  = i0 + (wid & 3) * 16;
    const int qi  = qw + ll;

    bf16x8 qf[2];
    {
        const __bf16* qp = qg + (size_t)(qw + ll) * QSZ + h * 64 + lg * 8;
        qf[0] = *reinterpret_cast<const bf16x8*>(qp);
        qf[1] = *reinterpret_cast<const bf16x8*>(qp + 32);
    }

    f32x4 o[4];
    #pragma unroll
    for (int dn = 0; dn < 4; dn++) o[dn] = (f32x4){0.f, 0.f, 0.f, 0.f};
    float l_run = 0.f;

    int jlo = i0 - (WINDOW - 1); if (jlo < 0) jlo = 0;
    int t0v = jlo & ~63;
    int tend = i0 + 64;

    const int srow = tid >> 3;
    const int sg   = (tid & 7) ^ (srow & 7);
    const int krow = (srow & 35) | ((srow & 8) << 1) | ((srow & 4) << 1) | ((srow & 16) >> 2);
    const __bf16* kp = kgl + (size_t)krow * KVSZ + kvh * 64 + sg * 8;
    const __bf16* vp = vTg + (size_t)(kvh * 64 + srow) * T_SEQ + sg * 8;

#define ASTAGE(buf, t)                                   \
    {                                                    \
        gll16(kp + (size_t)(t) * KVSZ, KSM(buf) + tid * 8); \
        gll16(vp + (t),                VSM(buf) + tid * 8); \
    }

    ASTAGE(0, t0v);
    if (t0v + 64 < tend) ASTAGE(1, t0v + 64);

    const int swl = ll & 7;
    const int u0 = (lg ^ swl) * 8;
    const int u1 = ((4 + lg) ^ swl) * 8;

    int cur = 0;
    for (int t = t0v; t < tend; t += 64) {
        if (t + 64 < tend) { WAITV(2); } else { WAITV(0); }
        RAW_BARRIER();
        __builtin_amdgcn_sched_barrier(0);
        if (t + 128 < tend) {
            int nb = cur + 2; if (nb >= 3) nb -= 3;
            ASTAGE(nb, t + 128);
        }

        bool active = (t <= qw + 15) && (t + 63 >= qw - (WINDOW - 1));
        if (active) {
            f32x4 sT[4];
            __builtin_amdgcn_s_setprio(1);
            #pragma unroll
            for (int kt = 0; kt < 4; kt++) {
                sT[kt] = (f32x4){0.f, 0.f, 0.f, 0.f};
                bf16x8 kf0 = *reinterpret_cast<const bf16x8*>(KSM(cur) + kt*1024 + ll*64 + u0);
                sT[kt] = __builtin_amdgcn_mfma_f32_16x16x32_bf16(kf0, qf[0], sT[kt], 0, 0, 0);
                bf16x8 kf1 = *reinterpret_cast<const bf16x8*>(KSM(cur) + kt*1024 + ll*64 + u1);
                sT[kt] = __builtin_amdgcn_mfma_f32_16x16x32_bf16(kf1, qf[1], sT[kt], 0, 0, 0);
            }
            __builtin_amdgcn_s_setprio(0);

            bool full = (t + 63 <= qw) && (t >= qw + 15 - (WINDOW - 1));
            float ts = 0.f;
            if (full) {
                #pragma unroll
                for (int kt = 0; kt < 4; kt++) {
                    #pragma unroll
                    for (int r = 0; r < 4; r++) {
                        float p = EXPS(sT[kt][r]);
                        sT[kt][r] = p;
                        ts += p;
                    }
                }
            } else {
                #pragma unroll
                for (int kt = 0; kt < 4; kt++) {
                    int jb = t + ((kt & 2) << 4) + ((kt & 1) << 2) + (lg << 3);
                    #pragma unroll
                    for (int r = 0; r < 4; r++) {
                        int j = jb + r;
                        bool ok = (j <= qi) && (qi - j < WINDOW);
                        float p = ok ? EXPS(sT[kt][r]) : 0.f;
                        sT[kt][r] = p;
                        ts += p;
                    }
                }
            }
            ts += __shfl_xor(ts, 16);
            ts += __shfl_xor(ts, 32);
            l_run += ts;

            __builtin_amdgcn_s_setprio(1);
            #pragma unroll
            for (int kt2 = 0; kt2 < 2; kt2++) {
                bf16x8 pa;
                #pragma unroll
                for (int r = 0; r < 4; r++) {
                    pa[r]     = (__bf16)sT[kt2*2][r];
                    pa[r + 4] = (__bf16)sT[kt2*2 + 1][r];
                }
                int uv = kt2 ? u1 : u0;
                #pragma unroll
                for (int dn = 0; dn < 4; dn++) {
                    bf16x8 vf = *reinterpret_cast<const bf16x8*>(VSM(cur) + dn*1024 + ll*64 + uv);
                    o[dn] = __builtin_amdgcn_mfma_f32_16x16x32_bf16(pa, vf, o[dn], 0, 0, 0);
                }
            }
            __builtin_amdgcn_s_setprio(0);
        }
        cur = (cur == 2) ? 0 : cur + 1;
    }
#undef ASTAGE
#undef KSM
#undef VSM

    float linv = 1.0f / l_run;
    float i0v = __shfl(linv, lg*4 + 0);
    float i1v = __shfl(linv, lg*4 + 1);
    float i2v = __shfl(linv, lg*4 + 2);
    float i3v = __shfl(linv, lg*4 + 3);
    #pragma unroll
    for (int dn = 0; dn < 4; dn++) {
        og[(size_t)(qw + lg*4 + 0) * QSZ + h*64 + dn*16 + ll] = (__bf16)(o[dn][0] * i0v);
        og[(size_t)(qw + lg*4 + 1) * QSZ + h*64 + dn*16 + ll] = (__bf16)(o[dn][1] * i1v);
        og[(size_t)(qw + lg*4 + 2) * QSZ + h*64 + dn*16 + ll] = (__bf16)(o[dn][2] * i2v);
        og[(size_t)(qw + lg*4 + 3) * QSZ + h*64 + dn*16 + ll] = (__bf16)(o[dn][3] * i3v);
    }
}

// ---------------- launch ----------------
extern "C" void kernel_launch(void* const* d_in, const int* in_sizes, int n_in,
                              void* d_out, int out_size, void* d_ws, size_t ws_size,
                              hipStream_t stream) {
    const int*   positions = (const int*)d_in[0];
    const float* hidden    = (const float*)d_in[1];
    const float* wqkv      = (const float*)d_in[2];
    const float* wo        = (const float*)d_in[3];
    float* out = (float*)d_out;

    char* ws = (char*)d_ws;
    __bf16* hidden_bf = (__bf16*)(ws);                       // 2048x2048
    __bf16* wqkv_t    = (__bf16*)(ws + 8388608);             // 2560x2048
    __bf16* wo_t      = (__bf16*)(ws + 18874368);            // 2048x2048
    __bf16* q_bf      = (__bf16*)(ws + 37748736);            // 2048x2048
    __bf16* k_bf      = (__bf16*)(ws + 46137344);            // 2048x256
    __bf16* vT_bf     = (__bf16*)(ws + 47185920);            // 256x2048 (V^T)
    __bf16* attn_bf   = (__bf16*)(ws + 48234496);            // 2048x2048
    float2* ropetab   = (float2*)(ws + 56623104);            // 2048x32 float2

    prep<<<dim3(5632), dim3(256), 0, stream>>>(
        (const float4*)hidden, (bf16x4*)hidden_bf, wqkv, wqkv_t, positions, ropetab);

    gemm_qkv<<<dim3(QKVN / 128, T_SEQ / 64), dim3(256), 0, stream>>>(
        hidden_bf, wqkv_t, ropetab, q_bf, k_bf, vT_bf);

    attn_fused<<<dim3(1536), dim3(512), 0, stream>>>(
        q_bf, k_bf, vT_bf, attn_bf, wo, wo_t);

    gemm_out<<<dim3(HIDDEN / 128, T_SEQ / 64), dim3(256), 0, stream>>>(
        attn_bf, wo_t, out, T_SEQ, HIDDEN, QSZ);
}